// Round 1
// baseline (80.792 us; speedup 1.0000x reference)
//
#include <hip/hip_runtime.h>
#include <math.h>

// KDE Gaussian, bandwidth 0.1:
//   out[b,m] = sum_n exp(-50 * ||s[b,n] - l[m]||^2), then normalize per batch.
// Rewritten for v_exp_f32:  exp(-50 d2) = exp2(W * d2), W = -50*log2(e).
// t = W*d2 = ax*sx + ay*sy + (W*|s|^2 + W*|l|^2)  -> 2 fma + 1 add per pair.
// exp2(t) == 0.0f exactly (even denormal) for t < -150 -> exact wave-level cull.

#define W_CONST  (-72.13475204444817f)   // -50 * log2(e)
#define T_CULL   (-150.0f)

constexpr int Bc = 4, Nc = 4096, Hc = 128, Wc = 128, Mc = Hc * Wc;
constexpr int CHUNK = 512, NCH = Nc / CHUNK;   // 8 sample-chunks for load balance
constexpr int TILES = 64;                      // 8x8 tiles of 16x16 grid points

__global__ __launch_bounds__(256) void kde_part(
        const float* __restrict__ samples, const float* __restrict__ locs,
        float* __restrict__ out, float* __restrict__ norm) {
    __shared__ float4 sh[CHUNK];   // (sx, sy, W*|s|^2, pad)
    __shared__ float wred[4];

    const int bid   = blockIdx.x;
    const int chunk = bid & (NCH - 1);
    const int tile  = (bid >> 3) & (TILES - 1);
    const int b     = bid >> 9;
    const int tid   = threadIdx.x;

    // Stage this chunk's samples into LDS with precomputed W*|s|^2.
    const float2* sp = (const float2*)samples + (b * Nc + chunk * CHUNK);
    for (int i = tid; i < CHUNK; i += 256) {
        float2 s = sp[i];
        sh[i] = make_float4(s.x, s.y, W_CONST * (s.x * s.x + s.y * s.y), 0.0f);
    }

    // Thread -> grid point. Each wave (64 lanes) covers a compact 8x8 patch
    // so the __any cull below is spatially tight.
    const int wave = tid >> 6, lane = tid & 63;
    const int gi = (tile >> 3) * 16 + (wave >> 1) * 8 + (lane >> 3);
    const int gj = (tile & 7) * 16 + (wave & 1) * 8 + (lane & 7);
    const int m  = gi * Wc + gj;

    const float lx = locs[2 * m], ly = locs[2 * m + 1];
    const float c0 = W_CONST * (lx * lx + ly * ly);
    const float ax = -2.0f * W_CONST * lx;
    const float ay = -2.0f * W_CONST * ly;

    __syncthreads();

    float a0 = 0.f, a1 = 0.f, a2 = 0.f, a3 = 0.f;
#pragma unroll 2
    for (int n = 0; n < CHUNK; n += 4) {
        const float4 s0 = sh[n + 0];
        const float4 s1 = sh[n + 1];
        const float4 s2 = sh[n + 2];
        const float4 s3 = sh[n + 3];
        const float t0 = fmaf(ax, s0.x, fmaf(ay, s0.y, s0.z + c0));
        const float t1 = fmaf(ax, s1.x, fmaf(ay, s1.y, s1.z + c0));
        const float t2 = fmaf(ax, s2.x, fmaf(ay, s2.y, s2.z + c0));
        const float t3 = fmaf(ax, s3.x, fmaf(ay, s3.y, s3.z + c0));
        const float mx = fmaxf(fmaxf(t0, t1), fmaxf(t2, t3));
        if (__any(mx > T_CULL)) {   // skipped terms are exactly 0.0f
            a0 += __builtin_exp2f(t0);
            a1 += __builtin_exp2f(t1);
            a2 += __builtin_exp2f(t2);
            a3 += __builtin_exp2f(t3);
        }
    }
    const float acc = (a0 + a1) + (a2 + a3);

    // Accumulate chunk partial into the output (8 chunks race per address;
    // fp reorder noise is ~ulp, far below the 2% validation threshold).
    atomicAdd(&out[b * Mc + m], acc);

    // Block partial sum for the per-batch normalizer.
    float v = acc;
#pragma unroll
    for (int off = 32; off > 0; off >>= 1) v += __shfl_down(v, off, 64);
    if (lane == 0) wred[wave] = v;
    __syncthreads();
    if (tid == 0) atomicAdd(&norm[b], (wred[0] + wred[1]) + (wred[2] + wred[3]));
}

__global__ __launch_bounds__(256) void kde_norm(float* __restrict__ out,
                                                const float* __restrict__ norm) {
    const int i = blockIdx.x * 256 + threadIdx.x;
    out[i] = out[i] / norm[i >> 14];   // Mc = 2^14
}

extern "C" void kernel_launch(void* const* d_in, const int* in_sizes, int n_in,
                              void* d_out, int out_size, void* d_ws, size_t ws_size,
                              hipStream_t stream) {
    const float* samples = (const float*)d_in[0];   // (B, N, 2) fp32
    const float* locs    = (const float*)d_in[1];   // (H, W, 2) fp32
    float* out  = (float*)d_out;                    // (B, H, W) fp32
    float* norm = (float*)d_ws;                     // 4 floats

    hipMemsetAsync(out, 0, (size_t)Bc * Mc * sizeof(float), stream);
    hipMemsetAsync(norm, 0, Bc * sizeof(float), stream);

    kde_part<<<Bc * TILES * NCH, 256, 0, stream>>>(samples, locs, out, norm);
    kde_norm<<<Bc * Mc / 256, 256, 0, stream>>>(out, norm);
}